// Round 2
// baseline (504.728 us; speedup 1.0000x reference)
//
#include <hip/hip_runtime.h>
#include <hip/hip_bf16.h>
#include <math.h>

#define HW   3136
#define NIMG 64
#define M_TOT (NIMG * HW)   // 200704

typedef __attribute__((ext_vector_type(8))) short bf16x8_t;
typedef __attribute__((ext_vector_type(4))) float f32x4_t;

__device__ __forceinline__ unsigned short f2bf(float f) {
  union { float f; unsigned u; } v; v.f = f;
  unsigned r = v.u + 0x7FFFu + ((v.u >> 16) & 1u);
  return (unsigned short)(r >> 16);
}
__device__ __forceinline__ float bf2f(unsigned short h) {
  union { unsigned u; float f; } v; v.u = ((unsigned)h) << 16;
  return v.f;
}

// ---------------- K0: swizzle weight [N][K] into MFMA B-fragment order ----
// frag fi = nt*(K/32)+kt ; element (j) of lane l  <->  n = nt*16+(l&15),
// k = kt*32 + (l>>4)*8 + j.  (Same labeling used for A-frag loads -> any
// consistent hw k-permutation cancels.)
__global__ void k0_swz(const float* __restrict__ wsrc, unsigned short* __restrict__ bsw,
                       int N, int K) {
  int idx = blockIdx.x * 256 + threadIdx.x;
  int total = (N / 16) * (K / 32) * 64;
  if (idx >= total) return;
  int l  = idx & 63;
  int fi = idx >> 6;
  int KT = K / 32;
  int nt = fi / KT, kt = fi - nt * KT;
  int nn = nt * 16 + (l & 15);
  int kb = kt * 32 + (l >> 4) * 8;
  const float* src = wsrc + (size_t)nn * K + kb;
  unsigned short* dst = bsw + (size_t)idx * 8;
#pragma unroll
  for (int j = 0; j < 8; j++) dst[j] = f2bf(src[j]);
}

// ---------------- K0c: fold GRN beta through w2 into bias ---------------
__global__ void k0_b2p(const float* __restrict__ w2, const float* __restrict__ grnb,
                       const float* __restrict__ b2, float* __restrict__ b2p) {
  int c = blockIdx.x * blockDim.x + threadIdx.x;
  if (c >= 96) return;
  float s = b2[c];
  const float* wr = w2 + (size_t)c * 384;
  for (int f = 0; f < 384; f++) s += grnb[f] * wr[f];
  b2p[c] = s;
}

// ---------------- K1: depthwise 7x7 conv + bias + LayerNorm -> A bf16 ----
// block: 16x16 pixel tile of one image, thread per pixel.
__global__ __launch_bounds__(256) void k1_dwln(
    const float* __restrict__ x, const float* __restrict__ dww,
    const float* __restrict__ dwb, const float* __restrict__ lng,
    const float* __restrict__ lnb, unsigned short* __restrict__ A) {
  __shared__ float st[2][22][24];
  __shared__ unsigned short dwv[256][100];  // 256 px * (96 bf16 + pad)
  __shared__ float lnp[192];
  const int n  = blockIdx.y;
  const int h0 = (blockIdx.x >> 2) * 16, w0 = (blockIdx.x & 3) * 16;
  const int t  = threadIdx.x;
  const int ty = t >> 4, tx = t & 15;
  const int h = h0 + ty, w = w0 + tx;
  const bool act = (h < 56) && (w < 56);
  if (t < 192) lnp[t] = (t < 96) ? lng[t] : lnb[t - 96];
  const float* xn = x + (size_t)n * 96 * HW;

  for (int c = 0; c < 96; c += 2) {
    __syncthreads();
    for (int idx = t; idx < 2 * 22 * 24; idx += 256) {
      int cc  = idx / (22 * 24);
      int rem = idx - cc * (22 * 24);
      int r = rem / 24, col = rem - r * 24;
      int hh = h0 - 3 + r, ww = w0 - 3 + col;
      float v = 0.f;
      if (col < 22 && (unsigned)hh < 56u && (unsigned)ww < 56u)
        v = xn[(size_t)(c + cc) * HW + hh * 56 + ww];
      st[cc][r][col] = v;
    }
    __syncthreads();
    if (act) {
      const float* wa = dww + c * 49;
      const float* wb = wa + 49;
      float a0 = 0.f, a1 = 0.f;
#pragma unroll
      for (int dy = 0; dy < 7; dy++) {
#pragma unroll
        for (int dx = 0; dx < 7; dx++) {
          a0 = fmaf(wa[dy * 7 + dx], st[0][ty + dy][tx + dx], a0);
          a1 = fmaf(wb[dy * 7 + dx], st[1][ty + dy][tx + dx], a1);
        }
      }
      a0 += dwb[c]; a1 += dwb[c + 1];
      unsigned pk = ((unsigned)f2bf(a1) << 16) | (unsigned)f2bf(a0);
      *(unsigned*)&dwv[t][c] = pk;
    }
  }
  __syncthreads();
  if (!act) return;

  uint2 rowv[24];
  const uint2* rp = (const uint2*)&dwv[t][0];
  float s = 0.f, ss = 0.f;
#pragma unroll
  for (int j = 0; j < 24; j++) {
    rowv[j] = rp[j];
    float v0 = bf2f((unsigned short)(rowv[j].x & 0xffffu));
    float v1 = bf2f((unsigned short)(rowv[j].x >> 16));
    float v2 = bf2f((unsigned short)(rowv[j].y & 0xffffu));
    float v3 = bf2f((unsigned short)(rowv[j].y >> 16));
    s  += (v0 + v1) + (v2 + v3);
    ss += v0 * v0 + v1 * v1 + v2 * v2 + v3 * v3;
  }
  float mu  = s * (1.f / 96.f);
  float var = ss * (1.f / 96.f) - mu * mu;
  float rs  = rsqrtf(var + 1e-6f);
  unsigned short* Ap = A + ((size_t)n * HW + (size_t)h * 56 + w) * 96;
#pragma unroll
  for (int j = 0; j < 24; j++) {
    int c = j * 4;
    float v0 = bf2f((unsigned short)(rowv[j].x & 0xffffu));
    float v1 = bf2f((unsigned short)(rowv[j].x >> 16));
    float v2 = bf2f((unsigned short)(rowv[j].y & 0xffffu));
    float v3 = bf2f((unsigned short)(rowv[j].y >> 16));
    float o0 = (v0 - mu) * rs * lnp[c + 0] + lnp[96 + c + 0];
    float o1 = (v1 - mu) * rs * lnp[c + 1] + lnp[96 + c + 1];
    float o2 = (v2 - mu) * rs * lnp[c + 2] + lnp[96 + c + 2];
    float o3 = (v3 - mu) * rs * lnp[c + 3] + lnp[96 + c + 3];
    uint2 u;
    u.x = (unsigned)f2bf(o0) | ((unsigned)f2bf(o1) << 16);
    u.y = (unsigned)f2bf(o2) | ((unsigned)f2bf(o3) << 16);
    *(uint2*)(Ap + c) = u;
  }
}

// ---------------- K2: GEMM1 (M x 384 x 96) + GELU + GRN partial sums ----
__global__ __launch_bounds__(256) void k2_gemm1(
    const unsigned short* __restrict__ A, const unsigned short* __restrict__ B1,
    const float* __restrict__ b1, unsigned short* __restrict__ y1,
    float* __restrict__ gx2) {
  __shared__ unsigned short yt[64][392];  // 384 + 8 pad (row = 784 B, 16B-aligned)
  const int t  = threadIdx.x;
  const int wv = t >> 6, l = t & 63;
  const int lg = l >> 4, lr = l & 15;
  const int m0 = blockIdx.x * 64;
  const int n  = m0 / HW;

  bf16x8_t af[4][3];
#pragma unroll
  for (int mt = 0; mt < 4; mt++) {
    const unsigned short* ap = A + (size_t)(m0 + mt * 16 + lr) * 96 + lg * 8;
#pragma unroll
    for (int kt = 0; kt < 3; kt++)
      af[mt][kt] = *(const bf16x8_t*)(ap + kt * 32);
  }

  for (int i = 0; i < 6; i++) {
    int nt = wv * 6 + i;
    bf16x8_t bf[3];
#pragma unroll
    for (int kt = 0; kt < 3; kt++)
      bf[kt] = *(const bf16x8_t*)(B1 + ((size_t)(nt * 3 + kt) * 64 + l) * 8);
    f32x4_t acc[4];
#pragma unroll
    for (int mt = 0; mt < 4; mt++) {
      f32x4_t a = {0.f, 0.f, 0.f, 0.f};
#pragma unroll
      for (int kt = 0; kt < 3; kt++)
        a = __builtin_amdgcn_mfma_f32_16x16x32_bf16(af[mt][kt], bf[kt], a, 0, 0, 0);
      acc[mt] = a;
    }
    int f0 = nt * 16;
    float bias = b1[f0 + lr];
    float s2 = 0.f;
#pragma unroll
    for (int mt = 0; mt < 4; mt++) {
#pragma unroll
      for (int r = 0; r < 4; r++) {
        float v = acc[mt][r] + bias;
        float g = 0.5f * v * (1.f + erff(v * 0.70710678118f));
        s2 += g * g;
        yt[mt * 16 + lg * 4 + r][f0 + lr] = f2bf(g);
      }
    }
    s2 += __shfl_xor(s2, 16);
    s2 += __shfl_xor(s2, 32);
    if (l < 16) atomicAdd(gx2 + n * 384 + f0 + l, s2);
  }
  __syncthreads();
  const size_t yb = (size_t)m0 * 384;
#pragma unroll
  for (int it = 0; it < 12; it++) {
    int id = t + it * 256;          // 3072 = 64 rows * 48 chunks(16B)
    int m = id / 48, ch = id - m * 48;
    uint4 d = *(const uint4*)&yt[m][ch * 8];
    *(uint4*)(y1 + yb + (size_t)m * 384 + ch * 8) = d;
  }
}

// ---------------- K3: GRN coefficients --------------------------------
__global__ void k3_coef(const float* __restrict__ gx2, const float* __restrict__ grng,
                        float* __restrict__ coef) {
  __shared__ float red[128];
  __shared__ float gxs[384];
  int n = blockIdx.x, t = threadIdx.x;
  float s = 0.f;
  for (int f = t; f < 384; f += 128) {
    float g = sqrtf(gx2[n * 384 + f]);
    gxs[f] = g; s += g;
  }
  red[t] = s; __syncthreads();
  for (int o = 64; o > 0; o >>= 1) {
    if (t < o) red[t] += red[t + o];
    __syncthreads();
  }
  float inv = 1.f / (red[0] * (1.f / 384.f) + 1e-6f);
  for (int f = t; f < 384; f += 128)
    coef[n * 384 + f] = 1.f + grng[f] * gxs[f] * inv;
}

// ---------------- K4: GRN-scale + GEMM2 (M x 96 x 384) + residual -------
__global__ __launch_bounds__(256) void k4_gemm2(
    const unsigned short* __restrict__ y1, const unsigned short* __restrict__ B2,
    const float* __restrict__ coef, const float* __restrict__ b2p,
    const float* __restrict__ x, float* __restrict__ out) {
  __shared__ float zt[96][68];  // row = 272 B (16B-aligned)
  const int t  = threadIdx.x;
  const int wv = t >> 6, l = t & 63;
  const int lg = l >> 4, lr = l & 15;
  const int m0 = blockIdx.x * 64;
  const int n  = m0 / HW, hw0 = m0 - n * HW;
  const float* cf = coef + n * 384;
  f32x4_t acc[6];
#pragma unroll
  for (int i = 0; i < 6; i++) acc[i] = (f32x4_t){0.f, 0.f, 0.f, 0.f};
  const unsigned short* ap0 = y1 + (size_t)(m0 + wv * 16 + lr) * 384;

  for (int kt = 0; kt < 12; kt++) {
    int kb = kt * 32 + lg * 8;
    bf16x8_t a = *(const bf16x8_t*)(ap0 + kb);
    float cv[8];
    *(float4*)&cv[0] = *(const float4*)(cf + kb);
    *(float4*)&cv[4] = *(const float4*)(cf + kb + 4);
    bf16x8_t as;
#pragma unroll
    for (int j = 0; j < 8; j++)
      as[j] = (short)f2bf(bf2f((unsigned short)a[j]) * cv[j]);
#pragma unroll
    for (int nt = 0; nt < 6; nt++) {
      bf16x8_t b = *(const bf16x8_t*)(B2 + ((size_t)(nt * 12 + kt) * 64 + l) * 8);
      acc[nt] = __builtin_amdgcn_mfma_f32_16x16x32_bf16(as, b, acc[nt], 0, 0, 0);
    }
  }
#pragma unroll
  for (int nt = 0; nt < 6; nt++) {
    int c = nt * 16 + lr;
#pragma unroll
    for (int r = 0; r < 4; r++)
      zt[c][wv * 16 + lg * 4 + r] = acc[nt][r];
  }
  __syncthreads();
#pragma unroll
  for (int it = 0; it < 6; it++) {
    int id = t + it * 256;  // 1536 = 96 c * 16 quads
    int c = id >> 4, mq = id & 15;
    float4 z = *(const float4*)&zt[c][mq * 4];
    size_t base = ((size_t)(n * 96 + c)) * HW + hw0 + mq * 4;
    float4 xv = *(const float4*)(x + base);
    float bp = b2p[c];
    float4 o;
    o.x = xv.x + z.x + bp;
    o.y = xv.y + z.y + bp;
    o.z = xv.z + z.z + bp;
    o.w = xv.w + z.w + bp;
    *(float4*)(out + base) = o;
  }
}

// ---------------- launch -----------------------------------------------
extern "C" void kernel_launch(void* const* d_in, const int* in_sizes, int n_in,
                              void* d_out, int out_size, void* d_ws, size_t ws_size,
                              hipStream_t stream) {
  const float* x    = (const float*)d_in[0];
  const float* dww  = (const float*)d_in[1];
  const float* dwb  = (const float*)d_in[2];
  const float* lng  = (const float*)d_in[3];
  const float* lnb  = (const float*)d_in[4];
  const float* w1   = (const float*)d_in[5];
  const float* b1   = (const float*)d_in[6];
  const float* grng = (const float*)d_in[7];
  const float* grnb = (const float*)d_in[8];
  const float* w2   = (const float*)d_in[9];
  const float* b2   = (const float*)d_in[10];
  float* out = (float*)d_out;

  char* ws = (char*)d_ws;
  size_t off = 0;
  auto alloc = [&](size_t bytes) {
    char* p = ws + off;
    off += (bytes + 255) & ~(size_t)255;
    return p;
  };
  unsigned short* Abuf = (unsigned short*)alloc((size_t)M_TOT * 96 * 2);
  unsigned short* y1   = (unsigned short*)alloc((size_t)M_TOT * 384 * 2);
  unsigned short* B1sw = (unsigned short*)alloc((size_t)384 * 96 * 2);
  unsigned short* B2sw = (unsigned short*)alloc((size_t)96 * 384 * 2);
  float* gx2  = (float*)alloc((size_t)64 * 384 * 4);
  float* coef = (float*)alloc((size_t)64 * 384 * 4);
  float* b2p  = (float*)alloc((size_t)96 * 4);
  if (off > ws_size) return;  // workspace too small; pivot next round

  hipMemsetAsync(gx2, 0, 64 * 384 * 4, stream);
  k0_swz<<<18, 256, 0, stream>>>(w1, B1sw, 384, 96);
  k0_swz<<<18, 256, 0, stream>>>(w2, B2sw, 96, 384);
  k0_b2p<<<1, 128, 0, stream>>>(w2, grnb, b2, b2p);
  k1_dwln<<<dim3(16, 64), 256, 0, stream>>>(x, dww, dwb, lng, lnb, Abuf);
  k2_gemm1<<<3136, 256, 0, stream>>>(Abuf, B1sw, b1, y1, gx2);
  k3_coef<<<64, 128, 0, stream>>>(gx2, grng, coef);
  k4_gemm2<<<3136, 256, 0, stream>>>(y1, B2sw, coef, b2p, x, out);
}

// Round 3
// 264.710 us; speedup vs baseline: 1.9067x; 1.9067x over previous
//
#include <hip/hip_runtime.h>
#include <hip/hip_bf16.h>
#include <math.h>

#define HW   3136
#define NIMG 64
#define M_TOT (NIMG * HW)   // 200704

typedef __attribute__((ext_vector_type(8))) short bf16x8_t;
typedef __attribute__((ext_vector_type(4))) float f32x4_t;

__device__ __forceinline__ unsigned short f2bf(float f) {
  union { float f; unsigned u; } v; v.f = f;
  unsigned r = v.u + 0x7FFFu + ((v.u >> 16) & 1u);
  return (unsigned short)(r >> 16);
}
__device__ __forceinline__ float bf2f(unsigned short h) {
  union { unsigned u; float f; } v; v.u = ((unsigned)h) << 16;
  return v.f;
}

// ---------------- K0: swizzle weight [N][K] into MFMA B-fragment order ----
__global__ void k0_swz(const float* __restrict__ wsrc, unsigned short* __restrict__ bsw,
                       int N, int K) {
  int idx = blockIdx.x * 256 + threadIdx.x;
  int total = (N / 16) * (K / 32) * 64;
  if (idx >= total) return;
  int l  = idx & 63;
  int fi = idx >> 6;
  int KT = K / 32;
  int nt = fi / KT, kt = fi - nt * KT;
  int nn = nt * 16 + (l & 15);
  int kb = kt * 32 + (l >> 4) * 8;
  const float* src = wsrc + (size_t)nn * K + kb;
  unsigned short* dst = bsw + (size_t)idx * 8;
#pragma unroll
  for (int j = 0; j < 8; j++) dst[j] = f2bf(src[j]);
}

// ---------------- K0c: fold GRN beta through w2 into bias ---------------
__global__ void k0_b2p(const float* __restrict__ w2, const float* __restrict__ grnb,
                       const float* __restrict__ b2, float* __restrict__ b2p) {
  int c = blockIdx.x * blockDim.x + threadIdx.x;
  if (c >= 96) return;
  float s = b2[c];
  const float* wr = w2 + (size_t)c * 384;
  for (int f = 0; f < 384; f++) s += grnb[f] * wr[f];
  b2p[c] = s;
}

// ---------------- K1a: depthwise 7x7 conv, one (n,c) plane per block ----
template<int ROWS>
__device__ __forceinline__ void dw_block(const float (*xs)[65], const float (&w)[49],
                                         float bias, int y0, int xc, float (&acc)[ROWS]) {
  float win[ROWS + 6][7];
#pragma unroll
  for (int rr = 0; rr < ROWS + 6; rr++)
#pragma unroll
    for (int dx = 0; dx < 7; dx++)
      win[rr][dx] = xs[y0 + rr][xc + dx];
#pragma unroll
  for (int py = 0; py < ROWS; py++) acc[py] = bias;
#pragma unroll
  for (int dy = 0; dy < 7; dy++)
#pragma unroll
    for (int dx = 0; dx < 7; dx++) {
      float wv = w[dy * 7 + dx];
#pragma unroll
      for (int py = 0; py < ROWS; py++)
        acc[py] = fmaf(wv, win[py + dy][dx], acc[py]);
    }
}

__global__ __launch_bounds__(256) void k1a_dwconv(
    const float* __restrict__ x, const float* __restrict__ dww,
    const float* __restrict__ dwb, unsigned short* __restrict__ conv) {
  __shared__ float xs[62][65];
  const int c = blockIdx.x, n = blockIdx.y;
  const int t = threadIdx.x;
  const float* xp = x + ((size_t)n * 96 + c) * HW;
  for (int i = t; i < 62 * 64; i += 256) {
    int r = i >> 6, col = i & 63;
    if (col < 62) {
      int h = r - 3, w = col - 3;
      float v = ((unsigned)h < 56u && (unsigned)w < 56u) ? xp[h * 56 + w] : 0.f;
      xs[r][col] = v;
    }
  }
  float w[49];
#pragma unroll
  for (int j = 0; j < 49; j++) w[j] = dww[c * 49 + j];
  const float bias = dwb[c];
  __syncthreads();
  const int xq = t & 63, yq = t >> 6;
  const int xc = xq < 56 ? xq : 55;
  unsigned short* op = conv + ((size_t)n * 96 + c) * HW + xq;
  const int ybase = yq * 14;
#pragma unroll
  for (int yb = 0; yb < 12; yb += 4) {
    float acc[4];
    dw_block<4>(xs, w, bias, ybase + yb, xc, acc);
    if (xq < 56) {
#pragma unroll
      for (int py = 0; py < 4; py++)
        op[(ybase + yb + py) * 56] = f2bf(acc[py]);
    }
  }
  {
    float acc[2];
    dw_block<2>(xs, w, bias, ybase + 12, xc, acc);
    if (xq < 56) {
#pragma unroll
      for (int py = 0; py < 2; py++)
        op[(ybase + 12 + py) * 56] = f2bf(acc[py]);
    }
  }
}

// ---------------- K1b: transpose NCHW->NHWC + LayerNorm -> A bf16 -------
__global__ __launch_bounds__(256) void k1b_lnT(
    const unsigned short* __restrict__ conv, const float* __restrict__ lng,
    const float* __restrict__ lnb, unsigned short* __restrict__ A) {
  __shared__ unsigned short ts[64][102];
  __shared__ float lnp[192];
  const int t = threadIdx.x;
  const int bid = blockIdx.x;
  const int n = bid / 49;
  const int hw0 = (bid - n * 49) * 64;
  if (t < 192) lnp[t] = (t < 96) ? lng[t] : lnb[t - 96];
  const unsigned short* cp0 = conv + (size_t)n * 96 * HW + hw0;
  for (int i = t; i < 96 * 32; i += 256) {
    int c = i >> 5, pxq = i & 31;
    unsigned u = *(const unsigned*)(cp0 + (size_t)c * HW + pxq * 2);
    ts[pxq * 2 + 0][c] = (unsigned short)(u & 0xffffu);
    ts[pxq * 2 + 1][c] = (unsigned short)(u >> 16);
  }
  __syncthreads();
  const int px = t >> 2, q = t & 3;
  unsigned vu[12];
  float s = 0.f, ss = 0.f;
#pragma unroll
  for (int j = 0; j < 12; j++) {
    vu[j] = *(const unsigned*)&ts[px][q * 24 + j * 2];
    float v0 = bf2f((unsigned short)(vu[j] & 0xffffu));
    float v1 = bf2f((unsigned short)(vu[j] >> 16));
    s += v0 + v1; ss += v0 * v0 + v1 * v1;
  }
  s  += __shfl_xor(s, 1);  s  += __shfl_xor(s, 2);
  ss += __shfl_xor(ss, 1); ss += __shfl_xor(ss, 2);
  float mu  = s * (1.f / 96.f);
  float var = ss * (1.f / 96.f) - mu * mu;
  float rs  = rsqrtf(var + 1e-6f);
  unsigned ou[12];
#pragma unroll
  for (int j = 0; j < 12; j++) {
    int ch = q * 24 + j * 2;
    float v0 = bf2f((unsigned short)(vu[j] & 0xffffu));
    float v1 = bf2f((unsigned short)(vu[j] >> 16));
    float o0 = (v0 - mu) * rs * lnp[ch] + lnp[96 + ch];
    float o1 = (v1 - mu) * rs * lnp[ch + 1] + lnp[96 + ch + 1];
    ou[j] = (unsigned)f2bf(o0) | ((unsigned)f2bf(o1) << 16);
  }
  unsigned short* Ap = A + ((size_t)n * HW + hw0 + px) * 96 + q * 24;
#pragma unroll
  for (int k = 0; k < 3; k++)
    *(uint4*)(Ap + k * 8) = *(const uint4*)&ou[k * 4];
}

// ---------------- K2: GEMM1 (M x 384 x 96) + GELU + GRN partial sums ----
__global__ __launch_bounds__(256) void k2_gemm1(
    const unsigned short* __restrict__ A, const unsigned short* __restrict__ B1,
    const float* __restrict__ b1, unsigned short* __restrict__ y1,
    float* __restrict__ gx2) {
  __shared__ unsigned short yt[64][392];
  const int t  = threadIdx.x;
  const int wv = t >> 6, l = t & 63;
  const int lg = l >> 4, lr = l & 15;
  const int m0 = blockIdx.x * 64;
  const int n  = m0 / HW;

  bf16x8_t af[4][3];
#pragma unroll
  for (int mt = 0; mt < 4; mt++) {
    const unsigned short* ap = A + (size_t)(m0 + mt * 16 + lr) * 96 + lg * 8;
#pragma unroll
    for (int kt = 0; kt < 3; kt++)
      af[mt][kt] = *(const bf16x8_t*)(ap + kt * 32);
  }

  for (int i = 0; i < 6; i++) {
    int nt = wv * 6 + i;
    bf16x8_t bf[3];
#pragma unroll
    for (int kt = 0; kt < 3; kt++)
      bf[kt] = *(const bf16x8_t*)(B1 + ((size_t)(nt * 3 + kt) * 64 + l) * 8);
    f32x4_t acc[4];
#pragma unroll
    for (int mt = 0; mt < 4; mt++) {
      f32x4_t a = {0.f, 0.f, 0.f, 0.f};
#pragma unroll
      for (int kt = 0; kt < 3; kt++)
        a = __builtin_amdgcn_mfma_f32_16x16x32_bf16(af[mt][kt], bf[kt], a, 0, 0, 0);
      acc[mt] = a;
    }
    int f0 = nt * 16;
    float bias = b1[f0 + lr];
    float s2 = 0.f;
#pragma unroll
    for (int mt = 0; mt < 4; mt++) {
#pragma unroll
      for (int r = 0; r < 4; r++) {
        float v = acc[mt][r] + bias;
        float g = 0.5f * v * (1.f + erff(v * 0.70710678118f));
        s2 += g * g;
        yt[mt * 16 + lg * 4 + r][f0 + lr] = f2bf(g);
      }
    }
    s2 += __shfl_xor(s2, 16);
    s2 += __shfl_xor(s2, 32);
    if (l < 16) atomicAdd(gx2 + n * 384 + f0 + l, s2);
  }
  __syncthreads();
  const size_t yb = (size_t)m0 * 384;
#pragma unroll
  for (int it = 0; it < 12; it++) {
    int id = t + it * 256;          // 3072 = 64 rows * 48 chunks(16B)
    int m = id / 48, ch = id - m * 48;
    uint4 d = *(const uint4*)&yt[m][ch * 8];
    *(uint4*)(y1 + yb + (size_t)m * 384 + ch * 8) = d;
  }
}

// ---------------- K3: GRN coefficients --------------------------------
__global__ void k3_coef(const float* __restrict__ gx2, const float* __restrict__ grng,
                        float* __restrict__ coef) {
  __shared__ float red[128];
  __shared__ float gxs[384];
  int n = blockIdx.x, t = threadIdx.x;
  float s = 0.f;
  for (int f = t; f < 384; f += 128) {
    float g = sqrtf(gx2[n * 384 + f]);
    gxs[f] = g; s += g;
  }
  red[t] = s; __syncthreads();
  for (int o = 64; o > 0; o >>= 1) {
    if (t < o) red[t] += red[t + o];
    __syncthreads();
  }
  float inv = 1.f / (red[0] * (1.f / 384.f) + 1e-6f);
  for (int f = t; f < 384; f += 128)
    coef[n * 384 + f] = 1.f + grng[f] * gxs[f] * inv;
}

// ---------------- K4: GRN-scale + GEMM2 (M x 96 x 384) + residual -------
__global__ __launch_bounds__(256) void k4_gemm2(
    const unsigned short* __restrict__ y1, const unsigned short* __restrict__ B2,
    const float* __restrict__ coef, const float* __restrict__ b2p,
    const float* __restrict__ x, float* __restrict__ out) {
  __shared__ float zt[96][68];
  const int t  = threadIdx.x;
  const int wv = t >> 6, l = t & 63;
  const int lg = l >> 4, lr = l & 15;
  const int m0 = blockIdx.x * 64;
  const int n  = m0 / HW, hw0 = m0 - n * HW;
  const float* cf = coef + n * 384;
  f32x4_t acc[6];
#pragma unroll
  for (int i = 0; i < 6; i++) acc[i] = (f32x4_t){0.f, 0.f, 0.f, 0.f};
  const unsigned short* ap0 = y1 + (size_t)(m0 + wv * 16 + lr) * 384;

  for (int kt = 0; kt < 12; kt++) {
    int kb = kt * 32 + lg * 8;
    bf16x8_t a = *(const bf16x8_t*)(ap0 + kb);
    float cv[8];
    *(float4*)&cv[0] = *(const float4*)(cf + kb);
    *(float4*)&cv[4] = *(const float4*)(cf + kb + 4);
    bf16x8_t as;
#pragma unroll
    for (int j = 0; j < 8; j++)
      as[j] = (short)f2bf(bf2f((unsigned short)a[j]) * cv[j]);
#pragma unroll
    for (int nt = 0; nt < 6; nt++) {
      bf16x8_t b = *(const bf16x8_t*)(B2 + ((size_t)(nt * 12 + kt) * 64 + l) * 8);
      acc[nt] = __builtin_amdgcn_mfma_f32_16x16x32_bf16(as, b, acc[nt], 0, 0, 0);
    }
  }
#pragma unroll
  for (int nt = 0; nt < 6; nt++) {
    int c = nt * 16 + lr;
#pragma unroll
    for (int r = 0; r < 4; r++)
      zt[c][wv * 16 + lg * 4 + r] = acc[nt][r];
  }
  __syncthreads();
#pragma unroll
  for (int it = 0; it < 6; it++) {
    int id = t + it * 256;  // 1536 = 96 c * 16 quads
    int c = id >> 4, mq = id & 15;
    float4 z = *(const float4*)&zt[c][mq * 4];
    size_t base = ((size_t)(n * 96 + c)) * HW + hw0 + mq * 4;
    float4 xv = *(const float4*)(x + base);
    float bp = b2p[c];
    float4 o;
    o.x = xv.x + z.x + bp;
    o.y = xv.y + z.y + bp;
    o.z = xv.z + z.z + bp;
    o.w = xv.w + z.w + bp;
    *(float4*)(out + base) = o;
  }
}

// ---------------- launch -----------------------------------------------
extern "C" void kernel_launch(void* const* d_in, const int* in_sizes, int n_in,
                              void* d_out, int out_size, void* d_ws, size_t ws_size,
                              hipStream_t stream) {
  const float* x    = (const float*)d_in[0];
  const float* dww  = (const float*)d_in[1];
  const float* dwb  = (const float*)d_in[2];
  const float* lng  = (const float*)d_in[3];
  const float* lnb  = (const float*)d_in[4];
  const float* w1   = (const float*)d_in[5];
  const float* b1   = (const float*)d_in[6];
  const float* grng = (const float*)d_in[7];
  const float* grnb = (const float*)d_in[8];
  const float* w2   = (const float*)d_in[9];
  const float* b2   = (const float*)d_in[10];
  float* out = (float*)d_out;

  char* ws = (char*)d_ws;
  size_t off = 0;
  auto alloc = [&](size_t bytes) {
    char* p = ws + off;
    off += (bytes + 255) & ~(size_t)255;
    return p;
  };
  unsigned short* Abuf = (unsigned short*)alloc((size_t)M_TOT * 96 * 2);
  unsigned short* y1   = (unsigned short*)alloc((size_t)M_TOT * 384 * 2);
  unsigned short* B1sw = (unsigned short*)alloc((size_t)384 * 96 * 2);
  unsigned short* B2sw = (unsigned short*)alloc((size_t)96 * 384 * 2);
  float* gx2  = (float*)alloc((size_t)64 * 384 * 4);
  float* coef = (float*)alloc((size_t)64 * 384 * 4);
  float* b2p  = (float*)alloc((size_t)96 * 4);
  if (off > ws_size) return;

  // conv buffer aliases y1 (y1 is written only later, in K2)
  unsigned short* convb = y1;

  hipMemsetAsync(gx2, 0, 64 * 384 * 4, stream);
  k0_swz<<<18, 256, 0, stream>>>(w1, B1sw, 384, 96);
  k0_swz<<<18, 256, 0, stream>>>(w2, B2sw, 96, 384);
  k0_b2p<<<1, 128, 0, stream>>>(w2, grnb, b2, b2p);
  k1a_dwconv<<<dim3(96, 64), 256, 0, stream>>>(x, dww, dwb, convb);
  k1b_lnT<<<3136, 256, 0, stream>>>(convb, lng, lnb, Abuf);
  k2_gemm1<<<3136, 256, 0, stream>>>(Abuf, B1sw, b1, y1, gx2);
  k3_coef<<<64, 128, 0, stream>>>(gx2, grng, coef);
  k4_gemm2<<<3136, 256, 0, stream>>>(y1, B2sw, coef, b2p, x, out);
}